// Round 15
// baseline (161.589 us; speedup 1.0000x reference)
//
#include <hip/hip_runtime.h>
#include <math.h>

#define N_NODES 10000
#define N_EDGES 320000
#define IN_FEATS 256
#define N_HEADS 4
#define N_UNITS 64
#define OUT_FEATS 47
#define NEG_SLOPE 0.2f
#define MAXD 128  // padded CSR stride; max in-degree ~17 sigma below this

typedef __attribute__((ext_vector_type(8))) short bf16x8;
typedef __attribute__((ext_vector_type(4))) float f32x4;

__device__ __forceinline__ float wave_reduce_sum(float v) {
#pragma unroll
  for (int s = 32; s > 0; s >>= 1) v += __shfl_down(v, s, 64);
  return __shfl(v, 0, 64);
}
__device__ __forceinline__ float wave_reduce_max(float v) {
#pragma unroll
  for (int s = 32; s > 0; s >>= 1) v = fmaxf(v, __shfl_down(v, s, 64));
  return __shfl(v, 0, 64);
}

__device__ __forceinline__ float lrelu_exp(float s) {
  s = (s > 0.f) ? s : NEG_SLOPE * s;
  return expf(s);
}

// fp32 -> bf16 round-to-nearest-even
__device__ __forceinline__ unsigned f2bf(float f) {
  unsigned u = __float_as_uint(f);
  return (u + 0x7FFFu + ((u >> 16) & 1u)) >> 16;
}

__device__ __forceinline__ float bflo(unsigned u) { return __uint_as_float(u << 16); }
__device__ __forceinline__ float bfhi(unsigned u) { return __uint_as_float(u & 0xFFFF0000u); }

// ---------------- K1: gemm1 (blocks 0..312) + CSR scatter (1250) + W2^T pack (48)
// + wa/wb (1). (byte-identical to round 14: B in registers, barrier-free k-loop)
__global__ __launch_bounds__(256) void k1_kernel(
    const float* __restrict__ features, const float* __restrict__ W1,
    const float* __restrict__ al1, const float* __restrict__ ar1,
    unsigned short* __restrict__ feat1h, float* __restrict__ el1, float* __restrict__ er1,
    const int* __restrict__ src, const int* __restrict__ dst, int* __restrict__ cnt,
    int* __restrict__ src_csr, const float* __restrict__ W2,
    unsigned short* __restrict__ W2t, const float* __restrict__ al2,
    const float* __restrict__ ar2, float* __restrict__ wa, float* __restrict__ wb) {
  __shared__ __align__(16) char smem[49152];
  int b = blockIdx.x;
  int t = threadIdx.x;

  if (b >= 313) {
    if (b < 1563) {  // ---- CSR scatter path ----
      int e = (b - 313) * 256 + t;
      if (e < N_EDGES) {
        int d = dst[e];
        int p = atomicAdd(&cnt[d], 1);
        if (p < MAXD) src_csr[d * MAXD + p] = src[e];
      }
    } else if (b < 1611) {  // ---- W2^T bf16 [48][256] pack ----
      int o = (b - 1563) * 256 + t;  // 0..12287
      int c = o >> 8;
      int k = o & 255;
      W2t[o] = (c < OUT_FEATS) ? (unsigned short)f2bf(W2[k * OUT_FEATS + c]) : 0;
    } else {  // ---- wa/wb ----
      float a = 0.f, r = 0.f;
      for (int c = 0; c < OUT_FEATS; ++c) {
        float wv = W2[t * OUT_FEATS + c];
        a += wv * al2[c];
        r += wv * ar2[c];
      }
      wa[t] = a;
      wb[t] = r;
    }
    return;
  }

  // ---- gemm path (one 32-row tile per block, B in registers, barrier-free k-loop)
  unsigned short* ldsA = (unsigned short*)smem;  // 16 KB
  float* ldsC = (float*)(smem + 16384);          // 32 KB epilogue (former B region)

  int n0 = b * 32;
  int lane = t & 63;
  int w = t >> 6;
  int quad = lane >> 4;

  const float4* feat4 = (const float4*)features;
#pragma unroll
  for (int i = 0; i < 8; ++i) {
    int idx = i * 256 + t;
    int m = idx >> 6;
    int kb4 = idx & 63;
    float4 f = make_float4(0.f, 0.f, 0.f, 0.f);
    if (n0 + m < N_NODES) f = feat4[(size_t)(n0 + m) * 64 + kb4];
    unsigned u0 = f2bf(f.x) | (f2bf(f.y) << 16);
    unsigned u1 = f2bf(f.z) | (f2bf(f.w) << 16);
    int kb = kb4 >> 1;
    int di = m * 256 + ((kb ^ (m & 7)) << 3) + ((kb4 & 1) << 2);
    *(uint2*)&ldsA[di] = make_uint2(u0, u1);
  }

  // per-thread B base: this thread's MFMA B-fragment (ks,nt,j) lives at
  // W1[(ks*32 + quad*8 + j)*256 + w*64 + nt*16 + (lane&15)]
  const float* wbase = W1 + w * 64 + (lane & 15);

  float pf[32];
#pragma unroll
  for (int nt = 0; nt < 4; ++nt)
#pragma unroll
    for (int j = 0; j < 8; ++j)
      pf[nt * 8 + j] = wbase[(quad * 8 + j) * 256 + nt * 16];

  bf16x8 cur[4];
#pragma unroll
  for (int nt = 0; nt < 4; ++nt) {
    uint4 pk;
    pk.x = f2bf(pf[nt * 8 + 0]) | (f2bf(pf[nt * 8 + 1]) << 16);
    pk.y = f2bf(pf[nt * 8 + 2]) | (f2bf(pf[nt * 8 + 3]) << 16);
    pk.z = f2bf(pf[nt * 8 + 4]) | (f2bf(pf[nt * 8 + 5]) << 16);
    pk.w = f2bf(pf[nt * 8 + 6]) | (f2bf(pf[nt * 8 + 7]) << 16);
    cur[nt] = *(bf16x8*)&pk;
  }
  __syncthreads();  // A staged (the ONLY k-loop-related barrier)

  f32x4 acc[2][4];
#pragma unroll
  for (int mt = 0; mt < 2; ++mt)
#pragma unroll
    for (int nt = 0; nt < 4; ++nt) acc[mt][nt] = 0.f;

  for (int ks = 0; ks < 8; ++ks) {
    if (ks < 7) {  // prefetch next k-step's own B fragments (fp32) during compute
#pragma unroll
      for (int nt = 0; nt < 4; ++nt)
#pragma unroll
        for (int j = 0; j < 8; ++j)
          pf[nt * 8 + j] = wbase[((ks + 1) * 32 + quad * 8 + j) * 256 + nt * 16];
    }
    bf16x8 af[2];
#pragma unroll
    for (int mt = 0; mt < 2; ++mt) {
      int m = mt * 16 + (lane & 15);
      int kb = ks * 4 + quad;
      af[mt] = *(const bf16x8*)&ldsA[m * 256 + ((kb ^ (m & 7)) << 3)];
    }
#pragma unroll
    for (int nt = 0; nt < 4; ++nt) {
#pragma unroll
      for (int mt = 0; mt < 2; ++mt)
        acc[mt][nt] =
            __builtin_amdgcn_mfma_f32_16x16x32_bf16(af[mt], cur[nt], acc[mt][nt], 0, 0, 0);
    }
    if (ks < 7) {  // pack prefetched fp32 -> bf16x8 regs (identical f2bf order)
#pragma unroll
      for (int nt = 0; nt < 4; ++nt) {
        uint4 pk;
        pk.x = f2bf(pf[nt * 8 + 0]) | (f2bf(pf[nt * 8 + 1]) << 16);
        pk.y = f2bf(pf[nt * 8 + 2]) | (f2bf(pf[nt * 8 + 3]) << 16);
        pk.z = f2bf(pf[nt * 8 + 4]) | (f2bf(pf[nt * 8 + 5]) << 16);
        pk.w = f2bf(pf[nt * 8 + 6]) | (f2bf(pf[nt * 8 + 7]) << 16);
        cur[nt] = *(bf16x8*)&pk;
      }
    }
  }

#pragma unroll
  for (int mt = 0; mt < 2; ++mt)
#pragma unroll
    for (int nt = 0; nt < 4; ++nt)
#pragma unroll
      for (int r = 0; r < 4; ++r)
        ldsC[(mt * 16 + quad * 4 + r) * 256 + w * 64 + nt * 16 + (lane & 15)] = acc[mt][nt][r];
  __syncthreads();

  int c = lane * 4;
  int r0 = w * 8;
  float4 alv = ((const float4*)al1)[lane];
  float4 arv = ((const float4*)ar1)[lane];
#pragma unroll
  for (int i = 0; i < 8; ++i) {
    int rl = r0 + i;
    int row = n0 + rl;
    float4 a = *(const float4*)&ldsC[rl * 256 + c];
    bool valid = row < N_NODES;
    if (valid) {
      unsigned p0 = f2bf(a.x) | (f2bf(a.y) << 16);
      unsigned p1 = f2bf(a.z) | (f2bf(a.w) << 16);
      *(uint2*)&feat1h[(size_t)row * 256 + c] = make_uint2(p0, p1);
    }
    float el = a.x * alv.x + a.y * alv.y + a.z * alv.z + a.w * alv.w;
    float er = a.x * arv.x + a.y * arv.y + a.z * arv.z + a.w * arv.w;
#pragma unroll
    for (int s = 8; s > 0; s >>= 1) {
      el += __shfl_down(el, s, 16);
      er += __shfl_down(er, s, 16);
    }
    if ((lane & 15) == 0 && valid) {
      el1[row * 4 + (lane >> 4)] = el;
      er1[row * 4 + (lane >> 4)] = er;
    }
  }
}

// ---------------- Layer 1 aggregate + FUSED layer-2 feature matvec ----------------
// Round-14 structure + NEW: W2s LDS staging DELETED. The fused matvec reads W2t
// directly from global (24 KB, L2-hot: every block reads the same table; each
// lane reads its row exactly once so LDS staging bought no reuse). This drops
// agg1's LDS 35.5 KB -> 10.25 KB (occupancy 4 -> 8 blocks/CU) and removes the
// block-wide __syncthreads (h2s is own-wave write->read, lgkmcnt-ordered).
__global__ __launch_bounds__(256) void agg1_kernel(
    const int* __restrict__ src_csr, const int* __restrict__ cnt,
    const unsigned short* __restrict__ feat1h, const float* __restrict__ el1,
    const float* __restrict__ er1, const float* __restrict__ wa,
    const float* __restrict__ wb, const unsigned short* __restrict__ W2t,
    unsigned short* __restrict__ feat2ph, float* __restrict__ el2,
    float* __restrict__ er2) {
  __shared__ unsigned short h2s[4][256];  // 2 KB, per-wave h2 row (bf16)
  __shared__ float4 sc1s[4][128];         // 8 KB, per-wave edge scores (4 heads)
  int t = threadIdx.x;
  int w = t >> 6;
  int n = blockIdx.x * 4 + w;  // grid 2500 * 4 waves = 10000 exactly
  int lane = t & 63;
  int half = lane >> 5;
  int hl = lane & 31;
  int head = hl >> 3;

  int deg = min(cnt[n], MAXD);
  const int* sc = src_csr + n * MAXD;

  // batch-load the whole padded neighbor list (slots >= deg are stale, never used)
  int sidx0 = sc[lane];
  int sidx1 = sc[64 + lane];

  // -------- per-edge score precompute (slot = lane), exp computed ONCE --------
  float4 er4 = ((const float4*)er1)[n];  // broadcast
  float4 s4 = make_float4(0.f, 0.f, 0.f, 0.f);
  if (lane < deg) {  // guarded load: stale sidx never dereferenced
    float4 el = ((const float4*)el1)[sidx0];
    s4.x = lrelu_exp(el.x + er4.x);
    s4.y = lrelu_exp(el.y + er4.y);
    s4.z = lrelu_exp(el.z + er4.z);
    s4.w = lrelu_exp(el.w + er4.w);
  }
  sc1s[w][lane] = s4;
  float4 t4 = make_float4(0.f, 0.f, 0.f, 0.f);
  if (deg > 64) {  // wave-uniform rare path (Poisson(32): ~never)
    if (64 + lane < deg) {
      float4 el = ((const float4*)el1)[sidx1];
      t4.x = lrelu_exp(el.x + er4.x);
      t4.y = lrelu_exp(el.y + er4.y);
      t4.z = lrelu_exp(el.z + er4.z);
      t4.w = lrelu_exp(el.w + er4.w);
    }
    sc1s[w][64 + lane] = t4;
  }
  // head denominators: 4-component wave reduce of (s4 + t4)
  float ex = s4.x + t4.x, ey = s4.y + t4.y, ez = s4.z + t4.z, ew = s4.w + t4.w;
#pragma unroll
  for (int s = 32; s > 0; s >>= 1) {
    ex += __shfl_down(ex, s, 64);
    ey += __shfl_down(ey, s, 64);
    ez += __shfl_down(ez, s, 64);
    ew += __shfl_down(ew, s, 64);
  }
  ex = __shfl(ex, 0, 64);
  ey = __shfl(ey, 0, 64);
  ez = __shfl(ez, 0, 64);
  ew = __shfl(ew, 0, 64);
  float esum = (head == 0) ? ex : (head == 1) ? ey : (head == 2) ? ez : ew;

  const float* sp = (const float*)&sc1s[w][0];  // scores as flat floats

  float acc[8];
#pragma unroll
  for (int r = 0; r < 8; ++r) acc[r] = 0.f;

  int i = 0;
  uint4 c0, c1, c2, c3;
  float b0, b1, b2, b3;
  if (deg >= 8) {  // prologue: load group 0 (wave-uniform branch)
    int j0 = half, j1 = 2 + half, j2 = 4 + half, j3 = 6 + half;
    int sn0 = __shfl(sidx0, j0, 64);
    int sn1 = __shfl(sidx0, j1, 64);
    int sn2 = __shfl(sidx0, j2, 64);
    int sn3 = __shfl(sidx0, j3, 64);
    b0 = sp[j0 * 4 + head];
    b1 = sp[j1 * 4 + head];
    b2 = sp[j2 * 4 + head];
    b3 = sp[j3 * 4 + head];
    c0 = *(const uint4*)&feat1h[(size_t)sn0 * 256 + hl * 8];
    c1 = *(const uint4*)&feat1h[(size_t)sn1 * 256 + hl * 8];
    c2 = *(const uint4*)&feat1h[(size_t)sn2 * 256 + hl * 8];
    c3 = *(const uint4*)&feat1h[(size_t)sn3 * 256 + hl * 8];
  }
  for (; i + 16 <= deg; i += 8) {  // issue group i+8, consume group i
    int k0 = i + 8 + half, k1 = i + 10 + half, k2 = i + 12 + half, k3 = i + 14 + half;
    int m0 = __shfl((k0 < 64) ? sidx0 : sidx1, k0 & 63, 64);
    int m1 = __shfl((k1 < 64) ? sidx0 : sidx1, k1 & 63, 64);
    int m2 = __shfl((k2 < 64) ? sidx0 : sidx1, k2 & 63, 64);
    int m3 = __shfl((k3 < 64) ? sidx0 : sidx1, k3 & 63, 64);
    float nb0 = sp[k0 * 4 + head];
    float nb1 = sp[k1 * 4 + head];
    float nb2 = sp[k2 * 4 + head];
    float nb3 = sp[k3 * 4 + head];
    uint4 n0 = *(const uint4*)&feat1h[(size_t)m0 * 256 + hl * 8];
    uint4 n1 = *(const uint4*)&feat1h[(size_t)m1 * 256 + hl * 8];
    uint4 n2 = *(const uint4*)&feat1h[(size_t)m2 * 256 + hl * 8];
    uint4 n3 = *(const uint4*)&feat1h[(size_t)m3 * 256 + hl * 8];
    acc[0] += b0 * bflo(c0.x) + b1 * bflo(c1.x) + b2 * bflo(c2.x) + b3 * bflo(c3.x);
    acc[1] += b0 * bfhi(c0.x) + b1 * bfhi(c1.x) + b2 * bfhi(c2.x) + b3 * bfhi(c3.x);
    acc[2] += b0 * bflo(c0.y) + b1 * bflo(c1.y) + b2 * bflo(c2.y) + b3 * bflo(c3.y);
    acc[3] += b0 * bfhi(c0.y) + b1 * bfhi(c1.y) + b2 * bfhi(c2.y) + b3 * bfhi(c3.y);
    acc[4] += b0 * bflo(c0.z) + b1 * bflo(c1.z) + b2 * bflo(c2.z) + b3 * bflo(c3.z);
    acc[5] += b0 * bfhi(c0.z) + b1 * bfhi(c1.z) + b2 * bfhi(c2.z) + b3 * bfhi(c3.z);
    acc[6] += b0 * bflo(c0.w) + b1 * bflo(c1.w) + b2 * bflo(c2.w) + b3 * bflo(c3.w);
    acc[7] += b0 * bfhi(c0.w) + b1 * bfhi(c1.w) + b2 * bfhi(c2.w) + b3 * bfhi(c3.w);
    c0 = n0;
    c1 = n1;
    c2 = n2;
    c3 = n3;
    b0 = nb0;
    b1 = nb1;
    b2 = nb2;
    b3 = nb3;
  }
  if (deg >= 8) {  // epilogue: consume the final prefetched group
    acc[0] += b0 * bflo(c0.x) + b1 * bflo(c1.x) + b2 * bflo(c2.x) + b3 * bflo(c3.x);
    acc[1] += b0 * bfhi(c0.x) + b1 * bfhi(c1.x) + b2 * bfhi(c2.x) + b3 * bfhi(c3.x);
    acc[2] += b0 * bflo(c0.y) + b1 * bflo(c1.y) + b2 * bflo(c2.y) + b3 * bflo(c3.y);
    acc[3] += b0 * bfhi(c0.y) + b1 * bfhi(c1.y) + b2 * bfhi(c2.y) + b3 * bfhi(c3.y);
    acc[4] += b0 * bflo(c0.z) + b1 * bflo(c1.z) + b2 * bflo(c2.z) + b3 * bflo(c3.z);
    acc[5] += b0 * bfhi(c0.z) + b1 * bfhi(c1.z) + b2 * bfhi(c2.z) + b3 * bfhi(c3.z);
    acc[6] += b0 * bflo(c0.w) + b1 * bflo(c1.w) + b2 * bflo(c2.w) + b3 * bflo(c3.w);
    acc[7] += b0 * bfhi(c0.w) + b1 * bfhi(c1.w) + b2 * bfhi(c2.w) + b3 * bfhi(c3.w);
    i += 8;
  }
  for (; i < deg; i += 2) {  // tail: shfl unconditional, loads guarded
    int j = i + half;
    int sn = __shfl((j < 64) ? sidx0 : sidx1, j & 63, 64);
    if (j < deg) {
      float aw = sp[j * 4 + head];
      uint4 u = *(const uint4*)&feat1h[(size_t)sn * 256 + hl * 8];
      acc[0] += aw * bflo(u.x);
      acc[1] += aw * bfhi(u.x);
      acc[2] += aw * bflo(u.y);
      acc[3] += aw * bfhi(u.y);
      acc[4] += aw * bflo(u.z);
      acc[5] += aw * bfhi(u.z);
      acc[6] += aw * bflo(u.w);
      acc[7] += aw * bfhi(u.w);
    }
  }

#pragma unroll
  for (int r = 0; r < 8; ++r) acc[r] += __shfl_down(acc[r], 32, 64);
  float inv = 1.f / fmaxf(esum, 1e-9f);

  float4 wa0 = ((const float4*)wa)[hl * 2];
  float4 wa1 = ((const float4*)wa)[hl * 2 + 1];
  float4 wb0 = ((const float4*)wb)[hl * 2];
  float4 wb1 = ((const float4*)wb)[hl * 2 + 1];
  float v[8];
#pragma unroll
  for (int j = 0; j < 8; ++j) {
    float x = acc[j] * inv;
    v[j] = (x > 0.f) ? x : expm1f(x);  // ELU
  }
  float elp = v[0] * wa0.x + v[1] * wa0.y + v[2] * wa0.z + v[3] * wa0.w +
              v[4] * wa1.x + v[5] * wa1.y + v[6] * wa1.z + v[7] * wa1.w;
  float erp = v[0] * wb0.x + v[1] * wb0.y + v[2] * wb0.z + v[3] * wb0.w +
              v[4] * wb1.x + v[5] * wb1.y + v[6] * wb1.z + v[7] * wb1.w;
  if (half) {
    elp = 0.f;
    erp = 0.f;
  }
  if (half == 0) {
    uint4 pk;
    pk.x = f2bf(v[0]) | (f2bf(v[1]) << 16);
    pk.y = f2bf(v[2]) | (f2bf(v[3]) << 16);
    pk.z = f2bf(v[4]) | (f2bf(v[5]) << 16);
    pk.w = f2bf(v[6]) | (f2bf(v[7]) << 16);
    *(uint4*)&h2s[w][hl * 8] = pk;  // own-wave LDS row; lgkmcnt orders reads below
  }
#pragma unroll
  for (int s = 32; s > 0; s >>= 1) {
    elp += __shfl_down(elp, s, 64);
    erp += __shfl_down(erp, s, 64);
  }
  if (lane == 0) {
    el2[n] = elp;
    er2[n] = erp;
  }

  // fused layer-2 matvec: lane c computes feat2[n][c] = sum_k h2[k]*W2[k][c].
  // W2t read DIRECTLY from global (L2-hot 24KB table, each row read once per
  // lane -> LDS staging bought nothing). h2s is own-wave data: no barrier.
  int cc = (lane < 48) ? lane : 47;
  const uint4* wrow = (const uint4*)(W2t + cc * 256);
  const unsigned short* hrow = h2s[w];
  float acc2 = 0.f;
#pragma unroll 4
  for (int k8 = 0; k8 < 32; ++k8) {
    uint4 wv = wrow[k8];
    uint4 hv = *(const uint4*)&hrow[k8 * 8];  // same addr all lanes: broadcast
    acc2 += bflo(wv.x) * bflo(hv.x) + bfhi(wv.x) * bfhi(hv.x);
    acc2 += bflo(wv.y) * bflo(hv.y) + bfhi(wv.y) * bfhi(hv.y);
    acc2 += bflo(wv.z) * bflo(hv.z) + bfhi(wv.z) * bfhi(hv.z);
    acc2 += bflo(wv.w) * bflo(hv.w) + bfhi(wv.w) * bfhi(hv.w);
  }
  float hi = __shfl_down(acc2, 1, 64);
  if (lane < 48 && !(lane & 1))
    ((unsigned*)feat2ph)[(size_t)n * 24 + (lane >> 1)] = f2bf(acc2) | (f2bf(hi) << 16);
}

// ---------------- Layer 2 aggregate + log_softmax: one WAVE per node --------------
// (byte-identical to round 14)
__global__ __launch_bounds__(256) void agg2_kernel(
    const int* __restrict__ src_csr, const int* __restrict__ cnt,
    const unsigned short* __restrict__ feat2ph, const float* __restrict__ el2,
    const float* __restrict__ er2, float* __restrict__ out) {
  __shared__ float sc2s[4][128];  // 2 KB, per-wave scalar edge scores
  int t = threadIdx.x;
  int w = t >> 6;
  int n = blockIdx.x * 4 + w;
  int lane = t & 63;
  int half = lane >> 5;
  int hl = lane & 31;
  int deg = min(cnt[n], MAXD);
  float ern = er2[n];
  const int* sc = src_csr + n * MAXD;
  const unsigned* f2 = (const unsigned*)feat2ph;
  bool act = hl < 24;

  int sidx0 = sc[lane];
  int sidx1 = sc[64 + lane];

  // -------- per-edge score precompute (slot = lane) --------
  float s0v = 0.f;
  if (lane < deg) s0v = lrelu_exp(el2[sidx0] + ern);
  sc2s[w][lane] = s0v;
  float s1v = 0.f;
  if (deg > 64) {  // wave-uniform rare path
    if (64 + lane < deg) s1v = lrelu_exp(el2[sidx1] + ern);
    sc2s[w][64 + lane] = s1v;
  }
  float esum = wave_reduce_sum(s0v + s1v);
  const float* sp = &sc2s[w][0];

  float a0 = 0.f, a1 = 0.f;
  int i = 0;
  unsigned c0 = 0, c1 = 0, c2 = 0, c3 = 0;
  float b0, b1, b2, b3;
  if (deg >= 8) {  // prologue: load group 0 (wave-uniform branch)
    int j0 = half, j1 = 2 + half, j2 = 4 + half, j3 = 6 + half;
    int sn0 = __shfl(sidx0, j0, 64);
    int sn1 = __shfl(sidx0, j1, 64);
    int sn2 = __shfl(sidx0, j2, 64);
    int sn3 = __shfl(sidx0, j3, 64);
    b0 = sp[j0];
    b1 = sp[j1];
    b2 = sp[j2];
    b3 = sp[j3];
    c0 = act ? f2[(size_t)sn0 * 24 + hl] : 0u;
    c1 = act ? f2[(size_t)sn1 * 24 + hl] : 0u;
    c2 = act ? f2[(size_t)sn2 * 24 + hl] : 0u;
    c3 = act ? f2[(size_t)sn3 * 24 + hl] : 0u;
  }
  for (; i + 16 <= deg; i += 8) {  // issue group i+8, consume group i
    int k0 = i + 8 + half, k1 = i + 10 + half, k2 = i + 12 + half, k3 = i + 14 + half;
    int m0 = __shfl((k0 < 64) ? sidx0 : sidx1, k0 & 63, 64);
    int m1 = __shfl((k1 < 64) ? sidx0 : sidx1, k1 & 63, 64);
    int m2 = __shfl((k2 < 64) ? sidx0 : sidx1, k2 & 63, 64);
    int m3 = __shfl((k3 < 64) ? sidx0 : sidx1, k3 & 63, 64);
    float nb0 = sp[k0];
    float nb1 = sp[k1];
    float nb2 = sp[k2];
    float nb3 = sp[k3];
    unsigned n0 = act ? f2[(size_t)m0 * 24 + hl] : 0u;
    unsigned n1 = act ? f2[(size_t)m1 * 24 + hl] : 0u;
    unsigned n2 = act ? f2[(size_t)m2 * 24 + hl] : 0u;
    unsigned n3 = act ? f2[(size_t)m3 * 24 + hl] : 0u;
    a0 += b0 * bflo(c0) + b1 * bflo(c1) + b2 * bflo(c2) + b3 * bflo(c3);
    a1 += b0 * bfhi(c0) + b1 * bfhi(c1) + b2 * bfhi(c2) + b3 * bfhi(c3);
    c0 = n0;
    c1 = n1;
    c2 = n2;
    c3 = n3;
    b0 = nb0;
    b1 = nb1;
    b2 = nb2;
    b3 = nb3;
  }
  if (deg >= 8) {  // epilogue: consume the final prefetched group
    a0 += b0 * bflo(c0) + b1 * bflo(c1) + b2 * bflo(c2) + b3 * bflo(c3);
    a1 += b0 * bfhi(c0) + b1 * bfhi(c1) + b2 * bfhi(c2) + b3 * bfhi(c3);
    i += 8;
  }
  for (; i < deg; i += 2) {  // tail: shfl unconditional, loads guarded
    int j = i + half;
    int sn = __shfl((j < 64) ? sidx0 : sidx1, j & 63, 64);
    if (j < deg) {
      float aw = sp[j];
      unsigned u = act ? f2[(size_t)sn * 24 + hl] : 0u;
      a0 += aw * bflo(u);
      a1 += aw * bfhi(u);
    }
  }

  a0 += __shfl_down(a0, 32, 64);
  a1 += __shfl_down(a1, 32, 64);
  float inv = 1.f / fmaxf(esum, 1e-9f);
  int c0i = hl * 2;
  int c1i = hl * 2 + 1;
  bool v0 = (half == 0) && (c0i < OUT_FEATS);
  bool v1 = (half == 0) && (c1i < OUT_FEATS);
  float l0 = a0 * inv;
  float l1 = a1 * inv;
  float m = fmaxf(v0 ? l0 : -INFINITY, v1 ? l1 : -INFINITY);
  m = wave_reduce_max(m);
  float exv = (v0 ? expf(l0 - m) : 0.f) + (v1 ? expf(l1 - m) : 0.f);
  float s = wave_reduce_sum(exv);
  float ls = logf(s);
  if (v0) out[n * OUT_FEATS + c0i] = l0 - m - ls;
  if (v1) out[n * OUT_FEATS + c1i] = l1 - m - ls;
}

extern "C" void kernel_launch(void* const* d_in, const int* in_sizes, int n_in,
                              void* d_out, int out_size, void* d_ws, size_t ws_size,
                              hipStream_t stream) {
  const float* features = (const float*)d_in[0];
  const int* src = (const int*)d_in[1];
  const int* dst = (const int*)d_in[2];
  const float* W1 = (const float*)d_in[3];
  const float* al1 = (const float*)d_in[4];
  const float* ar1 = (const float*)d_in[5];
  const float* W2 = (const float*)d_in[6];
  const float* al2 = (const float*)d_in[7];
  const float* ar2 = (const float*)d_in[8];
  float* out = (float*)d_out;

  char* ws = (char*)d_ws;
  size_t o = 0;
  auto alloc = [&](size_t bytes) {
    void* p = ws + o;
    o = (o + bytes + 255) & ~(size_t)255;
    return p;
  };
  unsigned short* feat1h = (unsigned short*)alloc((size_t)N_NODES * 256 * 2);
  float* el1 = (float*)alloc((size_t)N_NODES * 4 * 4);
  float* er1 = (float*)alloc((size_t)N_NODES * 4 * 4);
  unsigned short* feat2ph = (unsigned short*)alloc((size_t)N_NODES * 48 * 2);
  float* el2v = (float*)alloc((size_t)N_NODES * 4);
  float* er2v = (float*)alloc((size_t)N_NODES * 4);
  unsigned short* W2t = (unsigned short*)alloc((size_t)48 * 256 * 2);
  float* wa = (float*)alloc(256 * 4);
  float* wb = (float*)alloc(256 * 4);
  int* cnt = (int*)alloc((size_t)N_NODES * 4);
  int* src_csr = (int*)alloc((size_t)N_NODES * MAXD * 4);

  (void)hipMemsetAsync(cnt, 0, (size_t)N_NODES * 4, stream);

  k1_kernel<<<1612, 256, 0, stream>>>(features, W1, al1, ar1, feat1h, el1, er1, src, dst,
                                      cnt, src_csr, W2, W2t, al2, ar2, wa, wb);
  agg1_kernel<<<2500, 256, 0, stream>>>(src_csr, cnt, feat1h, el1, er1, wa, wb, W2t,
                                        feat2ph, el2v, er2v);
  agg2_kernel<<<2500, 256, 0, stream>>>(src_csr, cnt, feat2ph, el2v, er2v, out);
}

// Round 16
// 147.845 us; speedup vs baseline: 1.0930x; 1.0930x over previous
//
#include <hip/hip_runtime.h>
#include <math.h>

#define N_NODES 10000
#define N_EDGES 320000
#define IN_FEATS 256
#define N_HEADS 4
#define N_UNITS 64
#define OUT_FEATS 47
#define NEG_SLOPE 0.2f
#define MAXD 128  // padded CSR stride; max in-degree ~17 sigma below this

typedef __attribute__((ext_vector_type(8))) short bf16x8;
typedef __attribute__((ext_vector_type(4))) float f32x4;

__device__ __forceinline__ float wave_reduce_sum(float v) {
#pragma unroll
  for (int s = 32; s > 0; s >>= 1) v += __shfl_down(v, s, 64);
  return __shfl(v, 0, 64);
}
__device__ __forceinline__ float wave_reduce_max(float v) {
#pragma unroll
  for (int s = 32; s > 0; s >>= 1) v = fmaxf(v, __shfl_down(v, s, 64));
  return __shfl(v, 0, 64);
}

__device__ __forceinline__ float lrelu_exp(float s) {
  s = (s > 0.f) ? s : NEG_SLOPE * s;
  return expf(s);
}

// fp32 -> bf16 round-to-nearest-even
__device__ __forceinline__ unsigned f2bf(float f) {
  unsigned u = __float_as_uint(f);
  return (u + 0x7FFFu + ((u >> 16) & 1u)) >> 16;
}

__device__ __forceinline__ float bflo(unsigned u) { return __uint_as_float(u << 16); }
__device__ __forceinline__ float bfhi(unsigned u) { return __uint_as_float(u & 0xFFFF0000u); }

// ---------------- K1: gemm1 (blocks 0..312) + CSR scatter (1250) + W2^T pack (48)
// + wa/wb (1). (B in registers, barrier-free k-loop)
__global__ __launch_bounds__(256) void k1_kernel(
    const float* __restrict__ features, const float* __restrict__ W1,
    const float* __restrict__ al1, const float* __restrict__ ar1,
    unsigned short* __restrict__ feat1h, float* __restrict__ el1, float* __restrict__ er1,
    const int* __restrict__ src, const int* __restrict__ dst, int* __restrict__ cnt,
    int* __restrict__ src_csr, const float* __restrict__ W2,
    unsigned short* __restrict__ W2t, const float* __restrict__ al2,
    const float* __restrict__ ar2, float* __restrict__ wa, float* __restrict__ wb) {
  __shared__ __align__(16) char smem[49152];
  int b = blockIdx.x;
  int t = threadIdx.x;

  if (b >= 313) {
    if (b < 1563) {  // ---- CSR scatter path ----
      int e = (b - 313) * 256 + t;
      if (e < N_EDGES) {
        int d = dst[e];
        int p = atomicAdd(&cnt[d], 1);
        if (p < MAXD) src_csr[d * MAXD + p] = src[e];
      }
    } else if (b < 1611) {  // ---- W2^T bf16 [48][256] pack ----
      int o = (b - 1563) * 256 + t;  // 0..12287
      int c = o >> 8;
      int k = o & 255;
      W2t[o] = (c < OUT_FEATS) ? (unsigned short)f2bf(W2[k * OUT_FEATS + c]) : 0;
    } else {  // ---- wa/wb ----
      float a = 0.f, r = 0.f;
      for (int c = 0; c < OUT_FEATS; ++c) {
        float wv = W2[t * OUT_FEATS + c];
        a += wv * al2[c];
        r += wv * ar2[c];
      }
      wa[t] = a;
      wb[t] = r;
    }
    return;
  }

  // ---- gemm path (one 32-row tile per block, B in registers, barrier-free k-loop)
  unsigned short* ldsA = (unsigned short*)smem;  // 16 KB
  float* ldsC = (float*)(smem + 16384);          // 32 KB epilogue (former B region)

  int n0 = b * 32;
  int lane = t & 63;
  int w = t >> 6;
  int quad = lane >> 4;

  const float4* feat4 = (const float4*)features;
#pragma unroll
  for (int i = 0; i < 8; ++i) {
    int idx = i * 256 + t;
    int m = idx >> 6;
    int kb4 = idx & 63;
    float4 f = make_float4(0.f, 0.f, 0.f, 0.f);
    if (n0 + m < N_NODES) f = feat4[(size_t)(n0 + m) * 64 + kb4];
    unsigned u0 = f2bf(f.x) | (f2bf(f.y) << 16);
    unsigned u1 = f2bf(f.z) | (f2bf(f.w) << 16);
    int kb = kb4 >> 1;
    int di = m * 256 + ((kb ^ (m & 7)) << 3) + ((kb4 & 1) << 2);
    *(uint2*)&ldsA[di] = make_uint2(u0, u1);
  }

  // per-thread B base: this thread's MFMA B-fragment (ks,nt,j) lives at
  // W1[(ks*32 + quad*8 + j)*256 + w*64 + nt*16 + (lane&15)]
  const float* wbase = W1 + w * 64 + (lane & 15);

  float pf[32];
#pragma unroll
  for (int nt = 0; nt < 4; ++nt)
#pragma unroll
    for (int j = 0; j < 8; ++j)
      pf[nt * 8 + j] = wbase[(quad * 8 + j) * 256 + nt * 16];

  bf16x8 cur[4];
#pragma unroll
  for (int nt = 0; nt < 4; ++nt) {
    uint4 pk;
    pk.x = f2bf(pf[nt * 8 + 0]) | (f2bf(pf[nt * 8 + 1]) << 16);
    pk.y = f2bf(pf[nt * 8 + 2]) | (f2bf(pf[nt * 8 + 3]) << 16);
    pk.z = f2bf(pf[nt * 8 + 4]) | (f2bf(pf[nt * 8 + 5]) << 16);
    pk.w = f2bf(pf[nt * 8 + 6]) | (f2bf(pf[nt * 8 + 7]) << 16);
    cur[nt] = *(bf16x8*)&pk;
  }
  __syncthreads();  // A staged (the ONLY k-loop-related barrier)

  f32x4 acc[2][4];
#pragma unroll
  for (int mt = 0; mt < 2; ++mt)
#pragma unroll
    for (int nt = 0; nt < 4; ++nt) acc[mt][nt] = 0.f;

  for (int ks = 0; ks < 8; ++ks) {
    if (ks < 7) {  // prefetch next k-step's own B fragments (fp32) during compute
#pragma unroll
      for (int nt = 0; nt < 4; ++nt)
#pragma unroll
        for (int j = 0; j < 8; ++j)
          pf[nt * 8 + j] = wbase[((ks + 1) * 32 + quad * 8 + j) * 256 + nt * 16];
    }
    bf16x8 af[2];
#pragma unroll
    for (int mt = 0; mt < 2; ++mt) {
      int m = mt * 16 + (lane & 15);
      int kb = ks * 4 + quad;
      af[mt] = *(const bf16x8*)&ldsA[m * 256 + ((kb ^ (m & 7)) << 3)];
    }
#pragma unroll
    for (int nt = 0; nt < 4; ++nt) {
#pragma unroll
      for (int mt = 0; mt < 2; ++mt)
        acc[mt][nt] =
            __builtin_amdgcn_mfma_f32_16x16x32_bf16(af[mt], cur[nt], acc[mt][nt], 0, 0, 0);
    }
    if (ks < 7) {  // pack prefetched fp32 -> bf16x8 regs (identical f2bf order)
#pragma unroll
      for (int nt = 0; nt < 4; ++nt) {
        uint4 pk;
        pk.x = f2bf(pf[nt * 8 + 0]) | (f2bf(pf[nt * 8 + 1]) << 16);
        pk.y = f2bf(pf[nt * 8 + 2]) | (f2bf(pf[nt * 8 + 3]) << 16);
        pk.z = f2bf(pf[nt * 8 + 4]) | (f2bf(pf[nt * 8 + 5]) << 16);
        pk.w = f2bf(pf[nt * 8 + 6]) | (f2bf(pf[nt * 8 + 7]) << 16);
        cur[nt] = *(bf16x8*)&pk;
      }
    }
  }

#pragma unroll
  for (int mt = 0; mt < 2; ++mt)
#pragma unroll
    for (int nt = 0; nt < 4; ++nt)
#pragma unroll
      for (int r = 0; r < 4; ++r)
        ldsC[(mt * 16 + quad * 4 + r) * 256 + w * 64 + nt * 16 + (lane & 15)] = acc[mt][nt][r];
  __syncthreads();

  int c = lane * 4;
  int r0 = w * 8;
  float4 alv = ((const float4*)al1)[lane];
  float4 arv = ((const float4*)ar1)[lane];
#pragma unroll
  for (int i = 0; i < 8; ++i) {
    int rl = r0 + i;
    int row = n0 + rl;
    float4 a = *(const float4*)&ldsC[rl * 256 + c];
    bool valid = row < N_NODES;
    if (valid) {
      unsigned p0 = f2bf(a.x) | (f2bf(a.y) << 16);
      unsigned p1 = f2bf(a.z) | (f2bf(a.w) << 16);
      *(uint2*)&feat1h[(size_t)row * 256 + c] = make_uint2(p0, p1);
    }
    float el = a.x * alv.x + a.y * alv.y + a.z * alv.z + a.w * alv.w;
    float er = a.x * arv.x + a.y * arv.y + a.z * arv.z + a.w * arv.w;
#pragma unroll
    for (int s = 8; s > 0; s >>= 1) {
      el += __shfl_down(el, s, 16);
      er += __shfl_down(er, s, 16);
    }
    if ((lane & 15) == 0 && valid) {
      el1[row * 4 + (lane >> 4)] = el;
      er1[row * 4 + (lane >> 4)] = er;
    }
  }
}

// ---------------- Layer 1 aggregate + FUSED layer-2 feature matvec ----------------
// Cooperative W2s staging + barrier (round-15's global-W2t matvec regressed:
// 48 divergent 512B rows/wave vs broadcast LDS reads) + score precompute in LDS
// + one-group-ahead software-pipelined gather.
__global__ __launch_bounds__(256) void agg1_kernel(
    const int* __restrict__ src_csr, const int* __restrict__ cnt,
    const unsigned short* __restrict__ feat1h, const float* __restrict__ el1,
    const float* __restrict__ er1, const float* __restrict__ wa,
    const float* __restrict__ wb, const unsigned short* __restrict__ W2t,
    unsigned short* __restrict__ feat2ph, float* __restrict__ el2,
    float* __restrict__ er2) {
  __shared__ unsigned short W2s[48 * 264];  // 25344 B, padded rows (528B)
  __shared__ unsigned short h2s[4][256];    // 2 KB, per-wave h2 row (bf16)
  __shared__ float4 sc1s[4][128];           // 8 KB, per-wave edge scores (4 heads)
  int t = threadIdx.x;
  int w = t >> 6;
  int n = blockIdx.x * 4 + w;  // grid 2500 * 4 waves = 10000 exactly
  int lane = t & 63;
  int half = lane >> 5;
  int hl = lane & 31;
  int head = hl >> 3;

  // stage W2^T once per block (cooperative)
#pragma unroll
  for (int i = 0; i < 6; ++i) {
    int idx = i * 256 + t;  // 0..1535 uint4
    int row = idx >> 5;
    int col = idx & 31;
    *(uint4*)&W2s[row * 264 + col * 8] = ((const uint4*)W2t)[idx];
  }

  int deg = min(cnt[n], MAXD);
  const int* sc = src_csr + n * MAXD;

  // batch-load the whole padded neighbor list (slots >= deg are stale, never used)
  int sidx0 = sc[lane];
  int sidx1 = sc[64 + lane];

  // -------- per-edge score precompute (slot = lane), exp computed ONCE --------
  float4 er4 = ((const float4*)er1)[n];  // broadcast
  float4 s4 = make_float4(0.f, 0.f, 0.f, 0.f);
  if (lane < deg) {  // guarded load: stale sidx never dereferenced
    float4 el = ((const float4*)el1)[sidx0];
    s4.x = lrelu_exp(el.x + er4.x);
    s4.y = lrelu_exp(el.y + er4.y);
    s4.z = lrelu_exp(el.z + er4.z);
    s4.w = lrelu_exp(el.w + er4.w);
  }
  sc1s[w][lane] = s4;
  float4 t4 = make_float4(0.f, 0.f, 0.f, 0.f);
  if (deg > 64) {  // wave-uniform rare path (Poisson(32): ~never)
    if (64 + lane < deg) {
      float4 el = ((const float4*)el1)[sidx1];
      t4.x = lrelu_exp(el.x + er4.x);
      t4.y = lrelu_exp(el.y + er4.y);
      t4.z = lrelu_exp(el.z + er4.z);
      t4.w = lrelu_exp(el.w + er4.w);
    }
    sc1s[w][64 + lane] = t4;
  }
  // head denominators: 4-component wave reduce of (s4 + t4)
  float ex = s4.x + t4.x, ey = s4.y + t4.y, ez = s4.z + t4.z, ew = s4.w + t4.w;
#pragma unroll
  for (int s = 32; s > 0; s >>= 1) {
    ex += __shfl_down(ex, s, 64);
    ey += __shfl_down(ey, s, 64);
    ez += __shfl_down(ez, s, 64);
    ew += __shfl_down(ew, s, 64);
  }
  ex = __shfl(ex, 0, 64);
  ey = __shfl(ey, 0, 64);
  ez = __shfl(ez, 0, 64);
  ew = __shfl(ew, 0, 64);
  float esum = (head == 0) ? ex : (head == 1) ? ey : (head == 2) ? ez : ew;

  const float* sp = (const float*)&sc1s[w][0];  // scores as flat floats

  float acc[8];
#pragma unroll
  for (int r = 0; r < 8; ++r) acc[r] = 0.f;

  int i = 0;
  uint4 c0, c1, c2, c3;
  float b0, b1, b2, b3;
  if (deg >= 8) {  // prologue: load group 0 (wave-uniform branch)
    int j0 = half, j1 = 2 + half, j2 = 4 + half, j3 = 6 + half;
    int sn0 = __shfl(sidx0, j0, 64);
    int sn1 = __shfl(sidx0, j1, 64);
    int sn2 = __shfl(sidx0, j2, 64);
    int sn3 = __shfl(sidx0, j3, 64);
    b0 = sp[j0 * 4 + head];
    b1 = sp[j1 * 4 + head];
    b2 = sp[j2 * 4 + head];
    b3 = sp[j3 * 4 + head];
    c0 = *(const uint4*)&feat1h[(size_t)sn0 * 256 + hl * 8];
    c1 = *(const uint4*)&feat1h[(size_t)sn1 * 256 + hl * 8];
    c2 = *(const uint4*)&feat1h[(size_t)sn2 * 256 + hl * 8];
    c3 = *(const uint4*)&feat1h[(size_t)sn3 * 256 + hl * 8];
  }
  for (; i + 16 <= deg; i += 8) {  // issue group i+8, consume group i
    int k0 = i + 8 + half, k1 = i + 10 + half, k2 = i + 12 + half, k3 = i + 14 + half;
    int m0 = __shfl((k0 < 64) ? sidx0 : sidx1, k0 & 63, 64);
    int m1 = __shfl((k1 < 64) ? sidx0 : sidx1, k1 & 63, 64);
    int m2 = __shfl((k2 < 64) ? sidx0 : sidx1, k2 & 63, 64);
    int m3 = __shfl((k3 < 64) ? sidx0 : sidx1, k3 & 63, 64);
    float nb0 = sp[k0 * 4 + head];
    float nb1 = sp[k1 * 4 + head];
    float nb2 = sp[k2 * 4 + head];
    float nb3 = sp[k3 * 4 + head];
    uint4 n0 = *(const uint4*)&feat1h[(size_t)m0 * 256 + hl * 8];
    uint4 n1 = *(const uint4*)&feat1h[(size_t)m1 * 256 + hl * 8];
    uint4 n2 = *(const uint4*)&feat1h[(size_t)m2 * 256 + hl * 8];
    uint4 n3 = *(const uint4*)&feat1h[(size_t)m3 * 256 + hl * 8];
    acc[0] += b0 * bflo(c0.x) + b1 * bflo(c1.x) + b2 * bflo(c2.x) + b3 * bflo(c3.x);
    acc[1] += b0 * bfhi(c0.x) + b1 * bfhi(c1.x) + b2 * bfhi(c2.x) + b3 * bfhi(c3.x);
    acc[2] += b0 * bflo(c0.y) + b1 * bflo(c1.y) + b2 * bflo(c2.y) + b3 * bflo(c3.y);
    acc[3] += b0 * bfhi(c0.y) + b1 * bfhi(c1.y) + b2 * bfhi(c2.y) + b3 * bfhi(c3.y);
    acc[4] += b0 * bflo(c0.z) + b1 * bflo(c1.z) + b2 * bflo(c2.z) + b3 * bflo(c3.z);
    acc[5] += b0 * bfhi(c0.z) + b1 * bfhi(c1.z) + b2 * bfhi(c2.z) + b3 * bfhi(c3.z);
    acc[6] += b0 * bflo(c0.w) + b1 * bflo(c1.w) + b2 * bflo(c2.w) + b3 * bflo(c3.w);
    acc[7] += b0 * bfhi(c0.w) + b1 * bfhi(c1.w) + b2 * bfhi(c2.w) + b3 * bfhi(c3.w);
    c0 = n0;
    c1 = n1;
    c2 = n2;
    c3 = n3;
    b0 = nb0;
    b1 = nb1;
    b2 = nb2;
    b3 = nb3;
  }
  if (deg >= 8) {  // epilogue: consume the final prefetched group
    acc[0] += b0 * bflo(c0.x) + b1 * bflo(c1.x) + b2 * bflo(c2.x) + b3 * bflo(c3.x);
    acc[1] += b0 * bfhi(c0.x) + b1 * bfhi(c1.x) + b2 * bfhi(c2.x) + b3 * bfhi(c3.x);
    acc[2] += b0 * bflo(c0.y) + b1 * bflo(c1.y) + b2 * bflo(c2.y) + b3 * bflo(c3.y);
    acc[3] += b0 * bfhi(c0.y) + b1 * bfhi(c1.y) + b2 * bfhi(c2.y) + b3 * bfhi(c3.y);
    acc[4] += b0 * bflo(c0.z) + b1 * bflo(c1.z) + b2 * bflo(c2.z) + b3 * bflo(c3.z);
    acc[5] += b0 * bfhi(c0.z) + b1 * bfhi(c1.z) + b2 * bfhi(c2.z) + b3 * bfhi(c3.z);
    acc[6] += b0 * bflo(c0.w) + b1 * bflo(c1.w) + b2 * bflo(c2.w) + b3 * bflo(c3.w);
    acc[7] += b0 * bfhi(c0.w) + b1 * bfhi(c1.w) + b2 * bfhi(c2.w) + b3 * bfhi(c3.w);
    i += 8;
  }
  for (; i < deg; i += 2) {  // tail: shfl unconditional, loads guarded
    int j = i + half;
    int sn = __shfl((j < 64) ? sidx0 : sidx1, j & 63, 64);
    if (j < deg) {
      float aw = sp[j * 4 + head];
      uint4 u = *(const uint4*)&feat1h[(size_t)sn * 256 + hl * 8];
      acc[0] += aw * bflo(u.x);
      acc[1] += aw * bfhi(u.x);
      acc[2] += aw * bflo(u.y);
      acc[3] += aw * bfhi(u.y);
      acc[4] += aw * bflo(u.z);
      acc[5] += aw * bfhi(u.z);
      acc[6] += aw * bflo(u.w);
      acc[7] += aw * bfhi(u.w);
    }
  }

#pragma unroll
  for (int r = 0; r < 8; ++r) acc[r] += __shfl_down(acc[r], 32, 64);
  float inv = 1.f / fmaxf(esum, 1e-9f);

  float4 wa0 = ((const float4*)wa)[hl * 2];
  float4 wa1 = ((const float4*)wa)[hl * 2 + 1];
  float4 wb0 = ((const float4*)wb)[hl * 2];
  float4 wb1 = ((const float4*)wb)[hl * 2 + 1];
  float v[8];
#pragma unroll
  for (int j = 0; j < 8; ++j) {
    float x = acc[j] * inv;
    v[j] = (x > 0.f) ? x : expm1f(x);  // ELU
  }
  float elp = v[0] * wa0.x + v[1] * wa0.y + v[2] * wa0.z + v[3] * wa0.w +
              v[4] * wa1.x + v[5] * wa1.y + v[6] * wa1.z + v[7] * wa1.w;
  float erp = v[0] * wb0.x + v[1] * wb0.y + v[2] * wb0.z + v[3] * wb0.w +
              v[4] * wb1.x + v[5] * wb1.y + v[6] * wb1.z + v[7] * wb1.w;
  if (half) {
    elp = 0.f;
    erp = 0.f;
  }
  if (half == 0) {
    uint4 pk;
    pk.x = f2bf(v[0]) | (f2bf(v[1]) << 16);
    pk.y = f2bf(v[2]) | (f2bf(v[3]) << 16);
    pk.z = f2bf(v[4]) | (f2bf(v[5]) << 16);
    pk.w = f2bf(v[6]) | (f2bf(v[7]) << 16);
    *(uint4*)&h2s[w][hl * 8] = pk;  // h2 row (bf16) to LDS, no global round-trip
  }
#pragma unroll
  for (int s = 32; s > 0; s >>= 1) {
    elp += __shfl_down(elp, s, 64);
    erp += __shfl_down(erp, s, 64);
  }
  if (lane == 0) {
    el2[n] = elp;
    er2[n] = erp;
  }

  __syncthreads();  // W2s staged + all h2s rows written (no early exits)

  // fused layer-2 matvec: lane c computes feat2[n][c] = sum_k h2[k]*W2[k][c]
  int cc = (lane < 48) ? lane : 47;
  const unsigned short* wrow = &W2s[cc * 264];
  const unsigned short* hrow = h2s[w];
  float acc2 = 0.f;
#pragma unroll 4
  for (int k8 = 0; k8 < 32; ++k8) {
    uint4 wv = *(const uint4*)&wrow[k8 * 8];
    uint4 hv = *(const uint4*)&hrow[k8 * 8];  // same addr all lanes: broadcast
    acc2 += bflo(wv.x) * bflo(hv.x) + bfhi(wv.x) * bfhi(hv.x);
    acc2 += bflo(wv.y) * bflo(hv.y) + bfhi(wv.y) * bfhi(hv.y);
    acc2 += bflo(wv.z) * bflo(hv.z) + bfhi(wv.z) * bfhi(hv.z);
    acc2 += bflo(wv.w) * bflo(hv.w) + bfhi(wv.w) * bfhi(hv.w);
  }
  float hi = __shfl_down(acc2, 1, 64);
  if (lane < 48 && !(lane & 1))
    ((unsigned*)feat2ph)[(size_t)n * 24 + (lane >> 1)] = f2bf(acc2) | (f2bf(hi) << 16);
}

// ---------------- Layer 2 aggregate + log_softmax: one WAVE per node --------------
// Score precompute in LDS + one-group-ahead software pipeline.
__global__ __launch_bounds__(256) void agg2_kernel(
    const int* __restrict__ src_csr, const int* __restrict__ cnt,
    const unsigned short* __restrict__ feat2ph, const float* __restrict__ el2,
    const float* __restrict__ er2, float* __restrict__ out) {
  __shared__ float sc2s[4][128];  // 2 KB, per-wave scalar edge scores
  int t = threadIdx.x;
  int w = t >> 6;
  int n = blockIdx.x * 4 + w;
  int lane = t & 63;
  int half = lane >> 5;
  int hl = lane & 31;
  int deg = min(cnt[n], MAXD);
  float ern = er2[n];
  const int* sc = src_csr + n * MAXD;
  const unsigned* f2 = (const unsigned*)feat2ph;
  bool act = hl < 24;

  int sidx0 = sc[lane];
  int sidx1 = sc[64 + lane];

  // -------- per-edge score precompute (slot = lane) --------
  float s0v = 0.f;
  if (lane < deg) s0v = lrelu_exp(el2[sidx0] + ern);
  sc2s[w][lane] = s0v;
  float s1v = 0.f;
  if (deg > 64) {  // wave-uniform rare path
    if (64 + lane < deg) s1v = lrelu_exp(el2[sidx1] + ern);
    sc2s[w][64 + lane] = s1v;
  }
  float esum = wave_reduce_sum(s0v + s1v);
  const float* sp = &sc2s[w][0];

  float a0 = 0.f, a1 = 0.f;
  int i = 0;
  unsigned c0 = 0, c1 = 0, c2 = 0, c3 = 0;
  float b0, b1, b2, b3;
  if (deg >= 8) {  // prologue: load group 0 (wave-uniform branch)
    int j0 = half, j1 = 2 + half, j2 = 4 + half, j3 = 6 + half;
    int sn0 = __shfl(sidx0, j0, 64);
    int sn1 = __shfl(sidx0, j1, 64);
    int sn2 = __shfl(sidx0, j2, 64);
    int sn3 = __shfl(sidx0, j3, 64);
    b0 = sp[j0];
    b1 = sp[j1];
    b2 = sp[j2];
    b3 = sp[j3];
    c0 = act ? f2[(size_t)sn0 * 24 + hl] : 0u;
    c1 = act ? f2[(size_t)sn1 * 24 + hl] : 0u;
    c2 = act ? f2[(size_t)sn2 * 24 + hl] : 0u;
    c3 = act ? f2[(size_t)sn3 * 24 + hl] : 0u;
  }
  for (; i + 16 <= deg; i += 8) {  // issue group i+8, consume group i
    int k0 = i + 8 + half, k1 = i + 10 + half, k2 = i + 12 + half, k3 = i + 14 + half;
    int m0 = __shfl((k0 < 64) ? sidx0 : sidx1, k0 & 63, 64);
    int m1 = __shfl((k1 < 64) ? sidx0 : sidx1, k1 & 63, 64);
    int m2 = __shfl((k2 < 64) ? sidx0 : sidx1, k2 & 63, 64);
    int m3 = __shfl((k3 < 64) ? sidx0 : sidx1, k3 & 63, 64);
    float nb0 = sp[k0];
    float nb1 = sp[k1];
    float nb2 = sp[k2];
    float nb3 = sp[k3];
    unsigned n0 = act ? f2[(size_t)m0 * 24 + hl] : 0u;
    unsigned n1 = act ? f2[(size_t)m1 * 24 + hl] : 0u;
    unsigned n2 = act ? f2[(size_t)m2 * 24 + hl] : 0u;
    unsigned n3 = act ? f2[(size_t)m3 * 24 + hl] : 0u;
    a0 += b0 * bflo(c0) + b1 * bflo(c1) + b2 * bflo(c2) + b3 * bflo(c3);
    a1 += b0 * bfhi(c0) + b1 * bfhi(c1) + b2 * bfhi(c2) + b3 * bfhi(c3);
    c0 = n0;
    c1 = n1;
    c2 = n2;
    c3 = n3;
    b0 = nb0;
    b1 = nb1;
    b2 = nb2;
    b3 = nb3;
  }
  if (deg >= 8) {  // epilogue: consume the final prefetched group
    a0 += b0 * bflo(c0) + b1 * bflo(c1) + b2 * bflo(c2) + b3 * bflo(c3);
    a1 += b0 * bfhi(c0) + b1 * bfhi(c1) + b2 * bfhi(c2) + b3 * bfhi(c3);
    i += 8;
  }
  for (; i < deg; i += 2) {  // tail: shfl unconditional, loads guarded
    int j = i + half;
    int sn = __shfl((j < 64) ? sidx0 : sidx1, j & 63, 64);
    if (j < deg) {
      float aw = sp[j];
      unsigned u = act ? f2[(size_t)sn * 24 + hl] : 0u;
      a0 += aw * bflo(u);
      a1 += aw * bfhi(u);
    }
  }

  a0 += __shfl_down(a0, 32, 64);
  a1 += __shfl_down(a1, 32, 64);
  float inv = 1.f / fmaxf(esum, 1e-9f);
  int c0i = hl * 2;
  int c1i = hl * 2 + 1;
  bool v0 = (half == 0) && (c0i < OUT_FEATS);
  bool v1 = (half == 0) && (c1i < OUT_FEATS);
  float l0 = a0 * inv;
  float l1 = a1 * inv;
  float m = fmaxf(v0 ? l0 : -INFINITY, v1 ? l1 : -INFINITY);
  m = wave_reduce_max(m);
  float exv = (v0 ? expf(l0 - m) : 0.f) + (v1 ? expf(l1 - m) : 0.f);
  float s = wave_reduce_sum(exv);
  float ls = logf(s);
  if (v0) out[n * OUT_FEATS + c0i] = l0 - m - ls;
  if (v1) out[n * OUT_FEATS + c1i] = l1 - m - ls;
}

extern "C" void kernel_launch(void* const* d_in, const int* in_sizes, int n_in,
                              void* d_out, int out_size, void* d_ws, size_t ws_size,
                              hipStream_t stream) {
  const float* features = (const float*)d_in[0];
  const int* src = (const int*)d_in[1];
  const int* dst = (const int*)d_in[2];
  const float* W1 = (const float*)d_in[3];
  const float* al1 = (const float*)d_in[4];
  const float* ar1 = (const float*)d_in[5];
  const float* W2 = (const float*)d_in[6];
  const float* al2 = (const float*)d_in[7];
  const float* ar2 = (const float*)d_in[8];
  float* out = (float*)d_out;

  char* ws = (char*)d_ws;
  size_t o = 0;
  auto alloc = [&](size_t bytes) {
    void* p = ws + o;
    o = (o + bytes + 255) & ~(size_t)255;
    return p;
  };
  unsigned short* feat1h = (unsigned short*)alloc((size_t)N_NODES * 256 * 2);
  float* el1 = (float*)alloc((size_t)N_NODES * 4 * 4);
  float* er1 = (float*)alloc((size_t)N_NODES * 4 * 4);
  unsigned short* feat2ph = (unsigned short*)alloc((size_t)N_NODES * 48 * 2);
  float* el2v = (float*)alloc((size_t)N_NODES * 4);
  float* er2v = (float*)alloc((size_t)N_NODES * 4);
  unsigned short* W2t = (unsigned short*)alloc((size_t)48 * 256 * 2);
  float* wa = (float*)alloc(256 * 4);
  float* wb = (float*)alloc(256 * 4);
  int* cnt = (int*)alloc((size_t)N_NODES * 4);
  int* src_csr = (int*)alloc((size_t)N_NODES * MAXD * 4);

  (void)hipMemsetAsync(cnt, 0, (size_t)N_NODES * 4, stream);

  k1_kernel<<<1612, 256, 0, stream>>>(features, W1, al1, ar1, feat1h, el1, er1, src, dst,
                                      cnt, src_csr, W2, W2t, al2, ar2, wa, wb);
  agg1_kernel<<<2500, 256, 0, stream>>>(src_csr, cnt, feat1h, el1, er1, wa, wb, W2t,
                                        feat2ph, el2v, er2v);
  agg2_kernel<<<2500, 256, 0, stream>>>(src_csr, cnt, feat2ph, el2v, er2v, out);
}